// Round 5
// baseline (72.202 us; speedup 1.0000x reference)
//
#include <hip/hip_runtime.h>
#include <math.h>

#define W 384
#define H 384
#define NB 32
#define NPIX (W*H)
#define NROWS (NB*H)             // 12288

// K2 geometry: 1 wave per 128-col x 48-row chunk
#define CH 48
#define NCHUNK (H/CH)            // 8
#define CG 3                     // 128-col groups
#define BPI (CG*NCHUNK)          // 24 blocks per image
#define NBLK (NB*BPI)            // 768 = 3 per CU exactly
#define RCOLS 160                // ring row: P cols x0-17 .. x0+142
#define RDEPTH 32                // window [y-15, y+16] == 32 rows exactly

// K1: 4 rows per 256-thread block (1 row per wave)
#define K1_WAVES 4
#define NBLK1 (NROWS/K1_WAVES)   // 3072

// ---------------------------------------------------------------------------
// K1: row-wise inclusive prefix sums of mask -> P plane (fp32, in d_ws)
// ---------------------------------------------------------------------------
__global__ __launch_bounds__(256) void row_prefix_kernel(
    const float* __restrict__ m, float* __restrict__ P)
{
    __shared__ float buf[K1_WAVES][W];
    const int wave = threadIdx.x >> 6;
    const int lane = threadIdx.x & 63;
    const int row  = blockIdx.x * K1_WAVES + wave;

    const float* src = m + (size_t)row * W;
    float*       dst = P + (size_t)row * W;

    const int i0 = lane * 6;
    const float2* s2 = (const float2*)(src + i0);
    const float2 q0 = s2[0], q1 = s2[1], q2 = s2[2];

    const float s0 = q0.x;
    const float s1 = s0 + q0.y;
    const float s2v = s1 + q1.x;
    const float s3 = s2v + q1.y;
    const float s4 = s3 + q2.x;
    const float s5 = s4 + q2.y;

    float s = s5;
    #pragma unroll
    for (int d = 1; d < 64; d <<= 1) {
        float t = __shfl_up(s, d);
        if (lane >= d) s += t;
    }
    const float base = s - s5;

    buf[wave][i0+0] = base + s0;
    buf[wave][i0+1] = base + s1;
    buf[wave][i0+2] = base + s2v;
    buf[wave][i0+3] = base + s3;
    buf[wave][i0+4] = base + s4;
    buf[wave][i0+5] = base + s5;
    __syncthreads();

    const float4* bsrc = (const float4*)&buf[wave][0];
    float4*       bdst = (float4*)dst;
    bdst[lane] = bsrc[lane];
    if (lane < 32) bdst[lane + 64] = bsrc[lane + 64];
}

// ---------------------------------------------------------------------------
// K2: fused loss. One wave per 128x48 chunk; P rows staged in a 32-deep LDS
// ring; vertical box sums slide in registers; 12 LDS taps + 2 float2/row.
// ---------------------------------------------------------------------------
__global__ __launch_bounds__(64) void loss_kernel(
    const float* __restrict__ pred, const float* __restrict__ mask,
    const float* __restrict__ P, float* __restrict__ partials)
{
    __shared__ float ring[RDEPTH][RCOLS];    // 20,480 B

    const int lane = threadIdx.x;
    const int bid  = blockIdx.x;
    const int k    = bid >> 3;
    const int b    = (bid & 7) + 8 * (k / BPI);   // XCD swizzle: img%8 == XCD
    const int r2   = k % BPI;
    const int cg   = r2 % CG;
    const int ck   = r2 / CG;
    const int x0   = cg * 128;
    const int y0   = ck * CH;
    const int x    = x0 + 2*lane;                 // lane owns cols x, x+1

    const float* Pimg = P    + (size_t)b * NPIX;
    const float* mimg = mask + (size_t)b * NPIX;
    const float* pimg = pred + (size_t)b * NPIX;

    const int cA = x0 - 17 + lane;       // ring word -> P col mapping: w = c-x0+17
    const int cB = cA + 64;              // always in [47+x0-17, ...] >= 0
    const int cC = cA + 128;             // lane<32 only

    auto ingest = [&](int r) {
        float* dst = ring[r & (RDEPTH-1)];
        if (r >= 0 && r < H) {
            const float* Pr = Pimg + (size_t)r * W;
            dst[lane]      = (cA >= 0) ? Pr[min(cA, W-1)] : 0.0f;  // 0 for cols<0
            dst[lane + 64] = Pr[min(cB, W-1)];                     // clamp = P[383]
            if (lane < 32) dst[lane + 128] = Pr[min(cC, W-1)];
        } else {
            dst[lane] = 0.0f;
            dst[lane + 64] = 0.0f;
            if (lane < 32) dst[lane + 128] = 0.0f;
        }
    };

    const int wb = 2 * lane;
    // horizontal box pair for radius rad from ring row rrow:
    // h(col x+i) = Pr[x+i+rad] - Pr[x+i-rad-1], both via ring (pads handle clamps)
    auto hp = [&](int rrow, int rad, float& h0, float& h1) {
        const float* row = ring[rrow & (RDEPTH-1)];
        const float l0 = row[wb + 16 - rad];
        const float l1 = row[wb + 17 - rad];
        const float r0 = row[wb + 17 + rad];
        const float r1 = row[wb + 18 + rad];
        h0 = r0 - l0; h1 = r1 - l1;
    };

    // ---- warmup: ingest window rows [y0-15, y0+16] ------------------------
    for (int r = y0 - 15; r <= y0 + 16; ++r) ingest(r);

    // ---- init vertical sums at y0 -----------------------------------------
    float v3a=0.f, v3b=0.f, v15a=0.f, v15b=0.f, v31a=0.f, v31b=0.f;
    for (int d = -15; d <= 15; ++d) {
        const int r = y0 + d;
        float h0, h1;
        hp(r, 15, h0, h1); v31a += h0; v31b += h1;
        if (d >= -7 && d <= 7) { hp(r, 7, h0, h1); v15a += h0; v15b += h1; }
        if (d >= -1 && d <= 1) { hp(r, 1, h0, h1); v3a  += h0; v3b  += h1; }
    }

    // ---- main loop --------------------------------------------------------
    const float i9 = 1.0f/9.0f, i225 = 1.0f/225.0f, i961 = 1.0f/961.0f;
    float pw=0.f, pi=0.f, pu=0.f, pb=0.f, pm=0.f;

    for (int y = y0; y < y0 + CH; ++y) {
        const float2 mv = *(const float2*)(mimg + (size_t)y*W + x);
        const float2 pv = *(const float2*)(pimg + (size_t)y*W + x);
        {
            const float m = mv.x, p = pv.x;
            const float w = fabsf(v3a*i9 - m) + fabsf(v15a*i225 - m) + fabsf(v31a*i961 - m);
            const float weit = 1.0f + 0.5f*w*m;
            pw += weit; pi += p*m*weit; pu += (p+m)*weit;
            pb -= m*__logf(p) + (1.0f - m)*__logf(1.0f - p);
            pm += fabsf(p - m);
        }
        {
            const float m = mv.y, p = pv.y;
            const float w = fabsf(v3b*i9 - m) + fabsf(v15b*i225 - m) + fabsf(v31b*i961 - m);
            const float weit = 1.0f + 0.5f*w*m;
            pw += weit; pi += p*m*weit; pu += (p+m)*weit;
            pb -= m*__logf(p) + (1.0f - m)*__logf(1.0f - p);
            pm += fabsf(p - m);
        }
        // slide all three windows to center y+1 (taps precede the ingest that
        // overwrites slot (y-15)&31 -- same-wave LDS program order guarantees RAW)
        float a0,a1,q0,q1;
        hp(y+2,  1,  a0,a1); hp(y-1,  1,  q0,q1); v3a  += a0-q0; v3b  += a1-q1;
        hp(y+8,  7,  a0,a1); hp(y-7,  7,  q0,q1); v15a += a0-q0; v15b += a1-q1;
        hp(y+16, 15, a0,a1); hp(y-15, 15, q0,q1); v31a += a0-q0; v31b += a1-q1;
        ingest(y + 17);
    }

    // ---- deterministic butterfly reduce + store ---------------------------
    #pragma unroll
    for (int off = 32; off >= 1; off >>= 1) {
        pw += __shfl_xor(pw, off);
        pi += __shfl_xor(pi, off);
        pu += __shfl_xor(pu, off);
        pb += __shfl_xor(pb, off);
        pm += __shfl_xor(pm, off);
    }
    if (lane == 0) {
        float* o = partials + (size_t)(b * BPI + cg * NCHUNK + ck) * 8;
        o[0]=pw; o[1]=pi; o[2]=pu; o[3]=pb; o[4]=pm;
    }
}

// ---------------------------------------------------------------------------
// K3: finalize. 1 wave, fp64, fixed order -> deterministic scalar.
// ---------------------------------------------------------------------------
__global__ __launch_bounds__(64) void finalize_kernel(
    const float* __restrict__ partials, float* __restrict__ out)
{
    const int lane = threadIdx.x;

    double bsum = 0.0, msum = 0.0;
    for (int j = lane; j < NBLK; j += 64) {
        bsum += (double)partials[(size_t)j*8 + 3];
        msum += (double)partials[(size_t)j*8 + 4];
    }
    #pragma unroll
    for (int s = 32; s > 0; s >>= 1) {
        bsum += __shfl_down(bsum, s);
        msum += __shfl_down(msum, s);
    }

    double wiou = 0.0, ratio = 0.0;
    if (lane < NB) {
        double Sw = 0.0, Si = 0.0, Su = 0.0;
        for (int j = 0; j < BPI; ++j) {
            const float* pp = partials + (size_t)(lane*BPI + j)*8;
            Sw += (double)pp[0];
            Si += (double)pp[1];
            Su += (double)pp[2];
        }
        wiou  = 1.0 - Si/(Su - Si);
        ratio = Sw/(Sw - (double)NPIX);
    }
    #pragma unroll
    for (int s = 16; s > 0; s >>= 1) {
        wiou  += __shfl_down(wiou,  s);
        ratio += __shfl_down(ratio, s);
    }

    if (lane == 0) {
        const double tot = (double)NB * (double)NPIX;
        const double bce = bsum / tot;
        const double mae = msum / tot;
        const double loss = 0.7 * (bce + wiou/(double)NB + mae * ratio/(double)NB);
        out[0] = (float)loss;
    }
}

extern "C" void kernel_launch(void* const* d_in, const int* in_sizes, int n_in,
                              void* d_out, int out_size, void* d_ws, size_t ws_size,
                              hipStream_t stream) {
    const float* pred = (const float*)d_in[0];
    const float* mask = (const float*)d_in[1];
    float* out        = (float*)d_out;

    float* P        = (float*)d_ws;                                   // 18.87 MB
    float* partials = (float*)((char*)d_ws + (size_t)NB*NPIX*sizeof(float));

    row_prefix_kernel<<<dim3(NBLK1), dim3(256), 0, stream>>>(mask, P);
    loss_kernel<<<dim3(NBLK), dim3(64), 0, stream>>>(pred, mask, P, partials);
    finalize_kernel<<<dim3(1), dim3(64), 0, stream>>>(partials, out);
}

// Round 7
// 38.748 us; speedup vs baseline: 1.8634x; 1.8634x over previous
//
#include <hip/hip_runtime.h>
#include <hip/hip_fp16.h>
#include <math.h>

#define W 384
#define H 384
#define NB 32
#define NPIX (W*H)

#define BAND 32
#define NBANDS (H/BAND)            // 12
#define NBLK1 (NB*NBANDS)          // 384 blocks, 384 threads
#define LSTR 416                   // LDS band row: 16 zero pad | 384 | 16 replicate pad

#define RC 8                       // rows per wave in K2
#define CPI 72                     // K2 blocks per image (128 thr = 2 waves; 144 waves/img)
#define NBLK2 (NB*CPI)             // 2304

// ---------------------------------------------------------------------------
// K1: per 32-row band: row-prefix -> band 2D prefix S (in LDS) -> V_k planes
// V_k[y][x] = S[y][x+k] - S[y][x-k-1]  (band-local column prefix of h_k)
// stored fp16, horizontal zero-pad clamps baked in via LDS pads.
// ---------------------------------------------------------------------------
__global__ __launch_bounds__(384) void band_v_kernel(
    const float* __restrict__ mask,
    __half* __restrict__ V3, __half* __restrict__ V15, __half* __restrict__ V31)
{
    __shared__ float lds[BAND][LSTR];     // 53,248 B

    const int tid  = threadIdx.x;
    const int wave = tid >> 6;
    const int lane = tid & 63;
    const int bid  = blockIdx.x;
    const int b    = (bid & 7) + 8 * ((bid >> 3) / NBANDS);   // img%8 == XCD
    const int band = (bid >> 3) % NBANDS;
    const int y0   = band * BAND;

    const float* mimg = mask + (size_t)b * NPIX;

    // phase 0: zero the 16-col left pads (32 rows x 16 = 512 slots, 384 threads)
    if (tid < 512) { lds[tid >> 4][tid & 15] = 0.0f; }
    if (tid < 128) { const int s = tid + 384; lds[s >> 4][s & 15] = 0.0f; }

    // phase 1: row prefix of each band row into lds[r][16..399]
    {
        const int x0 = lane * 6;
        #pragma unroll
        for (int i = 0; i < 6; ++i) {
            const int r = wave + i * 6;
            if (r < BAND) {
                const float2* src = (const float2*)(mimg + (size_t)(y0 + r) * W + x0);
                const float2 q0 = src[0], q1 = src[1], q2 = src[2];
                const float s0 = q0.x;
                const float s1 = s0 + q0.y;
                const float s2 = s1 + q1.x;
                const float s3 = s2 + q1.y;
                const float s4 = s3 + q2.x;
                const float s5 = s4 + q2.y;
                float ss = s5;
                #pragma unroll
                for (int d = 1; d < 64; d <<= 1) {
                    float t = __shfl_up(ss, d);
                    if (lane >= d) ss += t;
                }
                const float base = ss - s5;
                float2* dst = (float2*)&lds[r][16 + x0];
                dst[0] = make_float2(base + s0, base + s1);
                dst[1] = make_float2(base + s2, base + s3);
                dst[2] = make_float2(base + s4, base + s5);
            }
        }
    }
    __syncthreads();

    // phase 2: in-place column accumulate (thread = col, serial down 32 rows)
    if (tid < W) {
        const int c = 16 + tid;
        float acc = 0.0f;
        #pragma unroll 4
        for (int r = 0; r < BAND; ++r) {
            acc += lds[r][c];
            lds[r][c] = acc;
        }
    }
    __syncthreads();

    // phase 3: right pads = S[r][383] (col 399) replicated to cols 400..415.
    // 512 slots but only 384 threads -> needs BOTH statements (R6 bug: second
    // statement was missing, leaving rows 24..31 pads uninitialized).
    if (tid < 512) {
        const int r = tid >> 4, j = tid & 15;
        lds[r][400 + j] = lds[r][399];
    }
    if (tid < 128) {
        const int s = tid + 384;
        const int r = s >> 4, j = s & 15;
        lds[r][400 + j] = lds[r][399];
    }
    __syncthreads();

    // phase 4: V taps + fp16 store (thread = col)
    if (tid < W) {
        const int c = 16 + tid;
        __half* v3  = V3  + (size_t)b * NPIX + (size_t)y0 * W + tid;
        __half* v15 = V15 + (size_t)b * NPIX + (size_t)y0 * W + tid;
        __half* v31 = V31 + (size_t)b * NPIX + (size_t)y0 * W + tid;
        #pragma unroll 4
        for (int r = 0; r < BAND; ++r) {
            const float* row = lds[r];
            v3 [(size_t)r * W] = __float2half(row[c + 1]  - row[c - 2]);
            v15[(size_t)r * W] = __float2half(row[c + 7]  - row[c - 8]);
            v31[(size_t)r * W] = __float2half(row[c + 15] - row[c - 16]);
        }
    }
}

// ---------------------------------------------------------------------------
// K2: fused loss. 2 cols/lane; 9 half2 taps + m,p float2 per pixel pair.
// box_k = V_k[y1] - fLo*V_k[y0c] + fC*V_k[ytop]   (band-local column prefixes)
// ---------------------------------------------------------------------------
__global__ __launch_bounds__(128) void loss_kernel(
    const float* __restrict__ pred, const float* __restrict__ mask,
    const __half* __restrict__ V3, const __half* __restrict__ V15,
    const __half* __restrict__ V31, float* __restrict__ partials)
{
    const int tid  = threadIdx.x;
    const int wave = tid >> 6;
    const int lane = tid & 63;
    const int bid  = blockIdx.x;
    const int b    = (bid & 7) + 8 * ((bid >> 3) / CPI);      // img%8 == XCD
    const int qq   = (bid >> 3) % CPI;
    const int widx = qq * 2 + wave;        // 0..143
    const int cg   = widx % 3;             // 128-col group
    const int rcid = widx / 3;             // 0..47
    const int x    = cg * 128 + 2 * lane;  // owns cols x, x+1
    const int yA   = rcid * RC;

    const __half* v3i  = V3  + (size_t)b * NPIX + x;
    const __half* v15i = V15 + (size_t)b * NPIX + x;
    const __half* v31i = V31 + (size_t)b * NPIX + x;
    const float*  mi   = mask + (size_t)b * NPIX + x;
    const float*  pi_  = pred + (size_t)b * NPIX + x;

    float pw = 0.f, pin = 0.f, pun = 0.f, pb = 0.f, pm = 0.f;
    const float i9 = 1.0f/9.0f, i225 = 1.0f/225.0f, i961 = 1.0f/961.0f;

    #pragma unroll
    for (int i = 0; i < RC; ++i) {
        const int y = yA + i;

        float b3a, b3b, b15a, b15b, b31a, b31b;
        {
            #define RAD_BOX(r, vplane, h0, h1)                                     \
            {                                                                      \
                const int y1  = min(y + (r), H - 1);                               \
                const int ylo = y - (r) - 1;                                       \
                const int y0c = ylo < 0 ? 0 : ylo;                                 \
                const int ytp = y0c | (BAND - 1);                                  \
                const float fLo = ylo >= 0 ? 1.0f : 0.0f;                          \
                const float fC  = (ylo >= 0 && (y0c >> 5) != (y1 >> 5)) ? 1.0f : 0.0f; \
                const __half2 h1v = *(const __half2*)(vplane + (size_t)y1  * W);   \
                const __half2 h0v = *(const __half2*)(vplane + (size_t)y0c * W);   \
                const __half2 htv = *(const __half2*)(vplane + (size_t)ytp * W);   \
                const float2 f1 = __half22float2(h1v);                             \
                const float2 f0 = __half22float2(h0v);                             \
                const float2 ft = __half22float2(htv);                             \
                h0 = f1.x - fLo * f0.x + fC * ft.x;                                \
                h1 = f1.y - fLo * f0.y + fC * ft.y;                                \
            }
            RAD_BOX(1,  v3i,  b3a,  b3b)
            RAD_BOX(7,  v15i, b15a, b15b)
            RAD_BOX(15, v31i, b31a, b31b)
            #undef RAD_BOX
        }

        const float2 mv = *(const float2*)(mi  + (size_t)y * W);
        const float2 pv = *(const float2*)(pi_ + (size_t)y * W);
        {
            const float m = mv.x, p = pv.x;
            const float w = fabsf(b3a*i9 - m) + fabsf(b15a*i225 - m) + fabsf(b31a*i961 - m);
            const float weit = 1.0f + 0.5f * w * m;
            pw += weit; pin += p*m*weit; pun += (p+m)*weit;
            pb -= m*__logf(p) + (1.0f - m)*__logf(1.0f - p);
            pm += fabsf(p - m);
        }
        {
            const float m = mv.y, p = pv.y;
            const float w = fabsf(b3b*i9 - m) + fabsf(b15b*i225 - m) + fabsf(b31b*i961 - m);
            const float weit = 1.0f + 0.5f * w * m;
            pw += weit; pin += p*m*weit; pun += (p+m)*weit;
            pb -= m*__logf(p) + (1.0f - m)*__logf(1.0f - p);
            pm += fabsf(p - m);
        }
    }

    // deterministic wave butterfly
    #pragma unroll
    for (int off = 32; off >= 1; off >>= 1) {
        pw  += __shfl_xor(pw,  off);
        pin += __shfl_xor(pin, off);
        pun += __shfl_xor(pun, off);
        pb  += __shfl_xor(pb,  off);
        pm  += __shfl_xor(pm,  off);
    }
    __shared__ float red[2][5];
    if (lane == 0) {
        red[wave][0]=pw; red[wave][1]=pin; red[wave][2]=pun; red[wave][3]=pb; red[wave][4]=pm;
    }
    __syncthreads();
    if (tid == 0) {
        float* o = partials + (size_t)bid * 8;
        o[0]=red[0][0]+red[1][0]; o[1]=red[0][1]+red[1][1]; o[2]=red[0][2]+red[1][2];
        o[3]=red[0][3]+red[1][3]; o[4]=red[0][4]+red[1][4];
    }
}

// ---------------------------------------------------------------------------
// K3: finalize. 256 threads, fp64, fixed order -> deterministic scalar.
// ---------------------------------------------------------------------------
__global__ __launch_bounds__(256) void finalize_kernel(
    const float* __restrict__ partials, float* __restrict__ out)
{
    __shared__ double sB[4], sM[4];
    __shared__ double sw_[NB], si_[NB], su_[NB];

    const int t = threadIdx.x;
    const int i = t >> 3;                 // image
    const int s = t & 7;

    double Sw=0, Si=0, Su=0, Bc=0, Ma=0;
    for (int k = s; k < CPI; k += 8) {
        const int bid = (i & 7) + (((i >> 3) * CPI + k) << 3);
        const float* pp = partials + (size_t)bid * 8;
        Sw += (double)pp[0]; Si += (double)pp[1]; Su += (double)pp[2];
        Bc += (double)pp[3]; Ma += (double)pp[4];
    }
    #pragma unroll
    for (int d = 4; d >= 1; d >>= 1) {
        Sw += __shfl_down(Sw, d);
        Si += __shfl_down(Si, d);
        Su += __shfl_down(Su, d);
    }
    if (s == 0) { sw_[i] = Sw; si_[i] = Si; su_[i] = Su; }

    #pragma unroll
    for (int d = 32; d >= 1; d >>= 1) {
        Bc += __shfl_down(Bc, d);
        Ma += __shfl_down(Ma, d);
    }
    if ((t & 63) == 0) { sB[t >> 6] = Bc; sM[t >> 6] = Ma; }
    __syncthreads();

    if (t < 64) {
        double wiou = 0.0, ratio = 0.0;
        if (t < NB) {
            const double w = sw_[t], ii = si_[t], u = su_[t];
            wiou  = 1.0 - ii / (u - ii);
            ratio = w / (w - (double)NPIX);
        }
        #pragma unroll
        for (int d = 32; d >= 1; d >>= 1) {
            wiou  += __shfl_down(wiou,  d);
            ratio += __shfl_down(ratio, d);
        }
        if (t == 0) {
            const double bt  = sB[0]+sB[1]+sB[2]+sB[3];
            const double mt  = sM[0]+sM[1]+sM[2]+sM[3];
            const double tot = (double)NB * (double)NPIX;
            const double bce = bt / tot;
            const double mae = mt / tot;
            out[0] = (float)(0.7 * (bce + wiou/(double)NB + mae * ratio/(double)NB));
        }
    }
}

extern "C" void kernel_launch(void* const* d_in, const int* in_sizes, int n_in,
                              void* d_out, int out_size, void* d_ws, size_t ws_size,
                              hipStream_t stream) {
    const float* pred = (const float*)d_in[0];
    const float* mask = (const float*)d_in[1];
    float* out        = (float*)d_out;

    // ws layout: V3 | V15 | V31 (each 32*384*384 fp16 = 4.72 MB) | partials
    const size_t vplane = (size_t)NB * NPIX;           // elements
    __half* V3  = (__half*)d_ws;
    __half* V15 = V3  + vplane;
    __half* V31 = V15 + vplane;
    float* partials = (float*)(V31 + vplane);          // 2304*8*4 = 73 KB

    band_v_kernel<<<dim3(NBLK1), dim3(384), 0, stream>>>(mask, V3, V15, V31);
    loss_kernel<<<dim3(NBLK2), dim3(128), 0, stream>>>(pred, mask, V3, V15, V31, partials);
    finalize_kernel<<<dim3(1), dim3(256), 0, stream>>>(partials, out);
}

// Round 8
// 34.595 us; speedup vs baseline: 2.0870x; 1.1200x over previous
//
#include <hip/hip_runtime.h>
#include <hip/hip_fp16.h>
#include <math.h>

#define W 384
#define H 384
#define NB 32
#define NPIX (W*H)

#define BAND 16
#define NBANDS (H/BAND)            // 24
#define NBLK1 (NB*NBANDS)          // 768 blocks = 3/CU exactly
#define LSTR 416                   // 16 zero pad | 384 | 16 replicate pad

#define RC 6                       // rows per wave in K2
#define CPI 96                     // K2 blocks per image (2 waves each; 192 waves/img)
#define NBLK2 (NB*CPI)             // 3072 = 12/CU, 24 waves/CU

// ---------------------------------------------------------------------------
// K1: per 16-row band: row-prefix -> band 2D prefix S (LDS, reg-chained) ->
// V_k[y][x] = S[y][x+k] - S[y][x-k-1]  (fp16, horizontal clamps via pads)
// ---------------------------------------------------------------------------
__global__ __launch_bounds__(384) void band_v_kernel(
    const float* __restrict__ mask,
    __half* __restrict__ V3, __half* __restrict__ V15, __half* __restrict__ V31)
{
    __shared__ float lds[BAND][LSTR];     // 26,624 B

    const int tid  = threadIdx.x;
    const int wave = tid >> 6;
    const int lane = tid & 63;
    const int bid  = blockIdx.x;
    const int b    = (bid & 7) + 8 * ((bid >> 3) / NBANDS);   // img%8 == XCD
    const int band = (bid >> 3) % NBANDS;
    const int y0   = band * BAND;

    const float* mimg = mask + (size_t)b * NPIX;

    // phase 0: zero the 16-col left pads (16 rows x 16 = 256 slots)
    if (tid < 256) { lds[tid >> 4][tid & 15] = 0.0f; }

    // phase 1: row prefix of each band row into lds[r][16..399]
    {
        const int x0 = lane * 6;
        #pragma unroll
        for (int i = 0; i < 3; ++i) {
            const int r = wave + i * 6;
            if (r < BAND) {
                const float2* src = (const float2*)(mimg + (size_t)(y0 + r) * W + x0);
                const float2 q0 = src[0], q1 = src[1], q2 = src[2];
                const float s0 = q0.x;
                const float s1 = s0 + q0.y;
                const float s2 = s1 + q1.x;
                const float s3 = s2 + q1.y;
                const float s4 = s3 + q2.x;
                const float s5 = s4 + q2.y;
                float ss = s5;
                #pragma unroll
                for (int d = 1; d < 64; d <<= 1) {
                    float t = __shfl_up(ss, d);
                    if (lane >= d) ss += t;
                }
                const float base = ss - s5;
                float2* dst = (float2*)&lds[r][16 + x0];
                dst[0] = make_float2(base + s0, base + s1);
                dst[1] = make_float2(base + s2, base + s3);
                dst[2] = make_float2(base + s4, base + s5);
            }
        }
    }
    __syncthreads();

    // phase 2: column prefix via registers (16 independent reads, reg chain,
    // 16 writes) -- no dependent LDS round-trip chain.
    {
        const int c = 16 + tid;            // tid in [0,384): every column
        float v[BAND];
        #pragma unroll
        for (int r = 0; r < BAND; ++r) v[r] = lds[r][c];
        float acc = 0.0f;
        #pragma unroll
        for (int r = 0; r < BAND; ++r) { acc += v[r]; v[r] = acc; }
        #pragma unroll
        for (int r = 0; r < BAND; ++r) lds[r][c] = v[r];
    }
    __syncthreads();

    // phase 3: right pads = S[r][383] (col 399) replicated to cols 400..415
    if (tid < 256) {
        const int r = tid >> 4, j = tid & 15;
        lds[r][400 + j] = lds[r][399];
    }
    __syncthreads();

    // phase 4: V taps + half2 store. thread -> (col pair, row half)
    {
        const int cp = tid % 192;          // col pair: cols 2cp, 2cp+1
        const int hf = tid / 192;          // rows hf*8 .. hf*8+7
        const int c0 = 16 + 2 * cp;
        const size_t obase = (size_t)b * NPIX + (size_t)y0 * W + 2 * cp;
        #pragma unroll
        for (int rr = 0; rr < 8; ++rr) {
            const int r = hf * 8 + rr;
            const float* R = lds[r];
            const __half2 h3  = __floats2half2_rn(R[c0+1]  - R[c0-2],  R[c0+2]  - R[c0-1]);
            const __half2 h15 = __floats2half2_rn(R[c0+7]  - R[c0-8],  R[c0+8]  - R[c0-7]);
            const __half2 h31 = __floats2half2_rn(R[c0+15] - R[c0-16], R[c0+16] - R[c0-15]);
            const size_t o = obase + (size_t)r * W;
            *(__half2*)(V3  + o) = h3;
            *(__half2*)(V15 + o) = h15;
            *(__half2*)(V31 + o) = h31;
        }
    }
}

// ---------------------------------------------------------------------------
// K2: fused loss. 2 cols/lane, 6 rows/wave; 10 half2 taps + m,p float2 per
// pixel-pair row. box_k composed from band-local column prefixes V_k.
// ---------------------------------------------------------------------------
__global__ __launch_bounds__(128) void loss_kernel(
    const float* __restrict__ pred, const float* __restrict__ mask,
    const __half* __restrict__ V3, const __half* __restrict__ V15,
    const __half* __restrict__ V31, float* __restrict__ partials)
{
    const int tid  = threadIdx.x;
    const int wave = tid >> 6;
    const int lane = tid & 63;
    const int bid  = blockIdx.x;
    const int b    = (bid & 7) + 8 * ((bid >> 3) / CPI);      // img%8 == XCD
    const int qq   = (bid >> 3) % CPI;
    const int widx = qq * 2 + wave;        // 0..191
    const int cg   = widx % 3;             // 128-col group
    const int rcid = widx / 3;             // 0..63
    const int x    = cg * 128 + 2 * lane;  // owns cols x, x+1
    const int yA   = rcid * RC;

    const __half* v3i  = V3  + (size_t)b * NPIX + x;
    const __half* v15i = V15 + (size_t)b * NPIX + x;
    const __half* v31i = V31 + (size_t)b * NPIX + x;
    const float*  mi   = mask + (size_t)b * NPIX + x;
    const float*  pi_  = pred + (size_t)b * NPIX + x;

    float pw = 0.f, pin = 0.f, pun = 0.f, pb = 0.f, pm = 0.f;
    const float i9 = 1.0f/9.0f, i225 = 1.0f/225.0f, i961 = 1.0f/961.0f;

    #pragma unroll
    for (int i = 0; i < RC; ++i) {
        const int y = yA + i;

        float b3a, b3b, b15a, b15b, b31a, b31b;
        // 3-tap form (span <= 15 rows -> at most 1 band crossing)
        #define RAD_BOX3(r, vp, h0, h1)                                          \
        {                                                                        \
            const int y1  = min(y + (r), H - 1);                                 \
            const int ylo = y - (r) - 1;                                         \
            const int y0c = ylo < 0 ? 0 : ylo;                                   \
            const int ytp = y0c | (BAND - 1);                                    \
            const float fLo = ylo >= 0 ? 1.0f : 0.0f;                            \
            const float fC  = (ylo >= 0 && (y0c >> 4) != (y1 >> 4)) ? 1.0f : 0.0f; \
            const float2 f1 = __half22float2(*(const __half2*)(vp + (size_t)y1  * W)); \
            const float2 f0 = __half22float2(*(const __half2*)(vp + (size_t)y0c * W)); \
            const float2 ft = __half22float2(*(const __half2*)(vp + (size_t)ytp * W)); \
            h0 = f1.x - fLo * f0.x + fC * ft.x;                                  \
            h1 = f1.y - fLo * f0.y + fC * ft.y;                                  \
        }
        RAD_BOX3(1, v3i,  b3a,  b3b)
        RAD_BOX3(7, v15i, b15a, b15b)
        #undef RAD_BOX3
        // 4-tap form for r=15 (span 31 rows -> up to 2 band crossings)
        {
            const int y1  = min(y + 15, H - 1);
            const int ylo = y - 16;
            const int y0c = ylo < 0 ? 0 : ylo;
            const int s   = ylo >= 0 ? (y0c >> 4) : 0;
            const int n   = (y1 >> 4) - s;
            const int rt1 = s * BAND + (BAND - 1);             // always <= 383
            const int rt2 = min(rt1 + BAND, H - 1);
            const float fLo = ylo >= 0 ? 1.0f : 0.0f;
            const float g1  = n >= 1 ? 1.0f : 0.0f;
            const float g2  = n >= 2 ? 1.0f : 0.0f;
            const float2 f1 = __half22float2(*(const __half2*)(v31i + (size_t)y1  * W));
            const float2 f0 = __half22float2(*(const __half2*)(v31i + (size_t)y0c * W));
            const float2 t1 = __half22float2(*(const __half2*)(v31i + (size_t)rt1 * W));
            const float2 t2 = __half22float2(*(const __half2*)(v31i + (size_t)rt2 * W));
            b31a = f1.x - fLo * f0.x + g1 * t1.x + g2 * t2.x;
            b31b = f1.y - fLo * f0.y + g1 * t1.y + g2 * t2.y;
        }

        const float2 mv = *(const float2*)(mi  + (size_t)y * W);
        const float2 pv = *(const float2*)(pi_ + (size_t)y * W);
        {
            const float m = mv.x, p = pv.x;
            const float w = fabsf(b3a*i9 - m) + fabsf(b15a*i225 - m) + fabsf(b31a*i961 - m);
            const float weit = 1.0f + 0.5f * w * m;
            pw += weit; pin += p*m*weit; pun += (p+m)*weit;
            pb -= m*__logf(p) + (1.0f - m)*__logf(1.0f - p);
            pm += fabsf(p - m);
        }
        {
            const float m = mv.y, p = pv.y;
            const float w = fabsf(b3b*i9 - m) + fabsf(b15b*i225 - m) + fabsf(b31b*i961 - m);
            const float weit = 1.0f + 0.5f * w * m;
            pw += weit; pin += p*m*weit; pun += (p+m)*weit;
            pb -= m*__logf(p) + (1.0f - m)*__logf(1.0f - p);
            pm += fabsf(p - m);
        }
    }

    // deterministic wave butterfly
    #pragma unroll
    for (int off = 32; off >= 1; off >>= 1) {
        pw  += __shfl_xor(pw,  off);
        pin += __shfl_xor(pin, off);
        pun += __shfl_xor(pun, off);
        pb  += __shfl_xor(pb,  off);
        pm  += __shfl_xor(pm,  off);
    }
    __shared__ float red[2][5];
    if (lane == 0) {
        red[wave][0]=pw; red[wave][1]=pin; red[wave][2]=pun; red[wave][3]=pb; red[wave][4]=pm;
    }
    __syncthreads();
    if (tid == 0) {
        float* o = partials + (size_t)bid * 8;
        o[0]=red[0][0]+red[1][0]; o[1]=red[0][1]+red[1][1]; o[2]=red[0][2]+red[1][2];
        o[3]=red[0][3]+red[1][3]; o[4]=red[0][4]+red[1][4];
    }
}

// ---------------------------------------------------------------------------
// K3: finalize. 256 threads, fp64, fixed order -> deterministic scalar.
// ---------------------------------------------------------------------------
__global__ __launch_bounds__(256) void finalize_kernel(
    const float* __restrict__ partials, float* __restrict__ out)
{
    __shared__ double sB[4], sM[4];
    __shared__ double sw_[NB], si_[NB], su_[NB];

    const int t = threadIdx.x;
    const int i = t >> 3;                 // image
    const int s = t & 7;

    double Sw=0, Si=0, Su=0, Bc=0, Ma=0;
    for (int k = s; k < CPI; k += 8) {
        const int bid = (i & 7) + (((i >> 3) * CPI + k) << 3);
        const float* pp = partials + (size_t)bid * 8;
        Sw += (double)pp[0]; Si += (double)pp[1]; Su += (double)pp[2];
        Bc += (double)pp[3]; Ma += (double)pp[4];
    }
    #pragma unroll
    for (int d = 4; d >= 1; d >>= 1) {
        Sw += __shfl_down(Sw, d);
        Si += __shfl_down(Si, d);
        Su += __shfl_down(Su, d);
    }
    if (s == 0) { sw_[i] = Sw; si_[i] = Si; su_[i] = Su; }

    #pragma unroll
    for (int d = 32; d >= 1; d >>= 1) {
        Bc += __shfl_down(Bc, d);
        Ma += __shfl_down(Ma, d);
    }
    if ((t & 63) == 0) { sB[t >> 6] = Bc; sM[t >> 6] = Ma; }
    __syncthreads();

    if (t < 64) {
        double wiou = 0.0, ratio = 0.0;
        if (t < NB) {
            const double w = sw_[t], ii = si_[t], u = su_[t];
            wiou  = 1.0 - ii / (u - ii);
            ratio = w / (w - (double)NPIX);
        }
        #pragma unroll
        for (int d = 32; d >= 1; d >>= 1) {
            wiou  += __shfl_down(wiou,  d);
            ratio += __shfl_down(ratio, d);
        }
        if (t == 0) {
            const double bt  = sB[0]+sB[1]+sB[2]+sB[3];
            const double mt  = sM[0]+sM[1]+sM[2]+sM[3];
            const double tot = (double)NB * (double)NPIX;
            const double bce = bt / tot;
            const double mae = mt / tot;
            out[0] = (float)(0.7 * (bce + wiou/(double)NB + mae * ratio/(double)NB));
        }
    }
}

extern "C" void kernel_launch(void* const* d_in, const int* in_sizes, int n_in,
                              void* d_out, int out_size, void* d_ws, size_t ws_size,
                              hipStream_t stream) {
    const float* pred = (const float*)d_in[0];
    const float* mask = (const float*)d_in[1];
    float* out        = (float*)d_out;

    // ws layout: V3 | V15 | V31 (each 32*384*384 fp16 = 4.72 MB) | partials
    const size_t vplane = (size_t)NB * NPIX;           // elements
    __half* V3  = (__half*)d_ws;
    __half* V15 = V3  + vplane;
    __half* V31 = V15 + vplane;
    float* partials = (float*)(V31 + vplane);          // 3072*8*4 = 96 KB

    band_v_kernel<<<dim3(NBLK1), dim3(384), 0, stream>>>(mask, V3, V15, V31);
    loss_kernel<<<dim3(NBLK2), dim3(128), 0, stream>>>(pred, mask, V3, V15, V31, partials);
    finalize_kernel<<<dim3(1), dim3(256), 0, stream>>>(partials, out);
}